// Round 6
// baseline (579.961 us; speedup 1.0000x reference)
//
#include <hip/hip_runtime.h>

#define HH 128
#define RNUM 8
#define CC 40
#define CAP 64                // padded edge slots per dst (P(deg>64) ~ 1e-19)
#define LDA 136               // LDS row stride (bf16): 128 + 8 pad
#define SRCMASK 0x7FFFFFF
#define DEGSTR 16             // deg counter stride in ints: 1 counter per 64-B line

typedef __attribute__((ext_vector_type(8))) short short8;
typedef __attribute__((ext_vector_type(4))) float floatx4;

__device__ __forceinline__ float u2f(unsigned u) {
    union { unsigned u; float f; } c;
    c.u = u;
    return c.f;
}
__device__ __forceinline__ unsigned short f2bf(float f) {
    union { float f; unsigned u; } c;
    c.f = f;
    return (unsigned short)((c.u + 0x7FFFu + ((c.u >> 16) & 1u)) >> 16);
}

// ---------------- edge bucketing: elist[d*64+p] = (rel<<27)|src ----------------
__global__ void fill_kernel(const int* __restrict__ src, const int* __restrict__ dst,
                            const int* __restrict__ et, int* __restrict__ deg,
                            int* __restrict__ elist, int E) {
    int e = blockIdx.x * blockDim.x + threadIdx.x;
    if (e < E) {
        int d = dst[e];
        int p = atomicAdd(&deg[(size_t)d * DEGSTR], 1);
        if (p < CAP) elist[(size_t)d * CAP + p] = (int)(((unsigned)et[e] << 27) | (unsigned)src[e]);
    }
}

// ---------------- Bt[c][n][k] = bf16(Bc[k][n]), c0=root2, c1..8=W2[r] ----------------
__global__ void tcast_kernel(const float* __restrict__ root2, const float* __restrict__ W2,
                             unsigned short* __restrict__ Bt) {
    int bid = blockIdx.x;
    int c = bid >> 5;
    int id = (bid & 31) * 256 + threadIdx.x;
    int n = id >> 6, kp = id & 63;
    const float* B = (c == 0) ? root2 : W2 + (size_t)(c - 1) * HH * HH;
    float g0 = B[(2 * kp) * HH + n];
    float g1 = B[(2 * kp + 1) * HH + n];
    unsigned v = (unsigned)f2bf(g0) | ((unsigned)f2bf(g1) << 16);
    *(unsigned*)(Bt + (size_t)c * HH * HH + n * HH + 2 * kp) = v;
}

// ---------------- layer 1: wave per dst; fp32 W1 gather (round-4 proven form) ----------------
__global__ void gather1_kernel(const int* __restrict__ deg, const int* __restrict__ elist,
                               const float* __restrict__ W1, const float* __restrict__ root1,
                               const float* __restrict__ b1, unsigned short* __restrict__ hbf,
                               int Nn) {
    int w = (blockIdx.x * blockDim.x + threadIdx.x) >> 6;
    if (w >= Nn) return;
    int lane = threadIdx.x & 63;
    int qid = lane >> 4, cl = lane & 15;      // quad gathers one 512 B fp32 row
    int dd = min(deg[(size_t)w * DEGSTR], CAP);
    int pk = elist[(size_t)w * CAP + lane];   // one coalesced 256 B load: slot per lane
    int myrel = (lane < dd) ? (int)((unsigned)pk >> 27) : 8;

    float myinv = 1.0f;
#pragma unroll
    for (int r = 0; r < 8; ++r) {
        unsigned long long m = __ballot(myrel == r);
        int c = __popcll(m);
        if (lane == r) myinv = 1.0f / fmaxf(1.0f, (float)c);
    }

    float s0[8] = {0.f, 0.f, 0.f, 0.f, 0.f, 0.f, 0.f, 0.f};
    float s1[8] = {0.f, 0.f, 0.f, 0.f, 0.f, 0.f, 0.f, 0.f};
    float s2[8] = {0.f, 0.f, 0.f, 0.f, 0.f, 0.f, 0.f, 0.f};
    float s3[8] = {0.f, 0.f, 0.f, 0.f, 0.f, 0.f, 0.f, 0.f};

#define GRP(G, S)                                                                 \
    {                                                                             \
        int j = ((G) << 2) + qid;                                                 \
        int jj = min(j, dd - 1);                                                  \
        int pkj = __shfl(pk, jj);                                                 \
        int rr = (int)((unsigned)pkj >> 27);                                      \
        float wt = __shfl(myinv, rr);                                             \
        int ss = pkj & SRCMASK;                                                   \
        const float* p = W1 + ((size_t)rr * Nn + ss) * HH + cl * 8;               \
        if (j < dd) {                                                             \
            float4 v0 = *(const float4*)p;                                        \
            float4 v1 = *(const float4*)(p + 4);                                  \
            S[0] += v0.x * wt; S[1] += v0.y * wt; S[2] += v0.z * wt; S[3] += v0.w * wt; \
            S[4] += v1.x * wt; S[5] += v1.y * wt; S[6] += v1.z * wt; S[7] += v1.w * wt; \
        }                                                                         \
    }

    int ng = (dd + 3) >> 2;
    int g = 0;
    for (; g + 3 < ng; g += 4) {
        GRP(g, s0);
        GRP(g + 1, s1);
        GRP(g + 2, s2);
        GRP(g + 3, s3);
    }
    for (; g < ng; ++g) GRP(g, s0);
#undef GRP

#pragma unroll
    for (int k = 0; k < 8; ++k) {
        s0[k] += s1[k] + s2[k] + s3[k];
        s0[k] += __shfl_xor(s0[k], 16);
        s0[k] += __shfl_xor(s0[k], 32);
    }

    if (qid == 0) {
        const float* rp = root1 + (size_t)w * HH + cl * 8;
        float4 r0 = *(const float4*)rp;
        float4 r1 = *(const float4*)(rp + 4);
        float4 c0 = *(const float4*)(b1 + cl * 8);
        float4 c1 = *(const float4*)(b1 + cl * 8 + 4);
        float o[8];
        o[0] = fmaxf(s0[0] + r0.x + c0.x, 0.f); o[1] = fmaxf(s0[1] + r0.y + c0.y, 0.f);
        o[2] = fmaxf(s0[2] + r0.z + c0.z, 0.f); o[3] = fmaxf(s0[3] + r0.w + c0.w, 0.f);
        o[4] = fmaxf(s0[4] + r1.x + c1.x, 0.f); o[5] = fmaxf(s0[5] + r1.y + c1.y, 0.f);
        o[6] = fmaxf(s0[6] + r1.z + c1.z, 0.f); o[7] = fmaxf(s0[7] + r1.w + c1.w, 0.f);
        ushort4 pk0, pk1;
        pk0.x = f2bf(o[0]); pk0.y = f2bf(o[1]); pk0.z = f2bf(o[2]); pk0.w = f2bf(o[3]);
        pk1.x = f2bf(o[4]); pk1.y = f2bf(o[5]); pk1.z = f2bf(o[6]); pk1.w = f2bf(o[7]);
        unsigned short* hp = hbf + (size_t)w * HH + cl * 8;
        *(ushort4*)hp = pk0;
        *(ushort4*)(hp + 4) = pk1;
    }
}

// ---------------- fused layer 2: aggregate (edge walk) + 9 GEMM passes + relu + final linear ----
// Per block: 32 dsts. AT[0] = h tile (root2 pass); AT[c]=mean over rel c-1.
// C[32x128] = sum_c AT[c] @ Bt[c]; h2 = relu(C+b2); out = h2 @ lin_w + lin_b.
__global__ __launch_bounds__(256, 2) void layer2_kernel(
    const int* __restrict__ deg, const int* __restrict__ elist,
    const unsigned short* __restrict__ hbf, const unsigned short* __restrict__ Bt,
    const float* __restrict__ b2, const float* __restrict__ lin_w,
    const float* __restrict__ lin_b, float* __restrict__ out, int Nn) {
    __shared__ unsigned short AT[9 * 32 * LDA];   // 9 tiles x 32 rows x 136 (78336 B)
    const int tid = threadIdx.x;
    const int lane = tid & 63, wv = tid >> 6;
    const int quad = lane >> 4, l16 = lane & 15;
    const int m0 = blockIdx.x * 32;

    // ---- stage h tile (AT[0]) ----
#pragma unroll
    for (int it = 0; it < 2; ++it) {
        int id = tid + it * 256;
        int rw = id >> 4, c8 = id & 15;
        uint4 v = make_uint4(0, 0, 0, 0);
        if (m0 + rw < Nn) v = *(const uint4*)(hbf + (size_t)(m0 + rw) * HH + c8 * 8);
        *(uint4*)(AT + rw * LDA + c8 * 8) = v;
    }

    // ---- edge walk: wave wv handles dsts wv*8 .. wv*8+7 (serial), lane = channel pair ----
    for (int i = 0; i < 8; ++i) {
        int dl = wv * 8 + i;
        int d = m0 + dl;
        int dd = 0, pk = 0;
        if (d < Nn) {
            dd = min(deg[(size_t)d * DEGSTR], CAP);
            pk = elist[(size_t)d * CAP + lane];
        }
        float a0x = 0.f, a0y = 0.f, a1x = 0.f, a1y = 0.f, a2x = 0.f, a2y = 0.f, a3x = 0.f, a3y = 0.f;
        float a4x = 0.f, a4y = 0.f, a5x = 0.f, a5y = 0.f, a6x = 0.f, a6y = 0.f, a7x = 0.f, a7y = 0.f;
        int c0 = 0, c1 = 0, c2 = 0, c3 = 0, c4 = 0, c5 = 0, c6 = 0, c7 = 0;

#define ACCE(P, U)                                                             \
    {                                                                          \
        unsigned rr_ = (unsigned)(P) >> 27;                                    \
        float f0_ = u2f((U) << 16), f1_ = u2f((U) & 0xFFFF0000u);              \
        switch (rr_) {                                                         \
            case 0: a0x += f0_; a0y += f1_; ++c0; break;                       \
            case 1: a1x += f0_; a1y += f1_; ++c1; break;                       \
            case 2: a2x += f0_; a2y += f1_; ++c2; break;                       \
            case 3: a3x += f0_; a3y += f1_; ++c3; break;                       \
            case 4: a4x += f0_; a4y += f1_; ++c4; break;                       \
            case 5: a5x += f0_; a5y += f1_; ++c5; break;                       \
            case 6: a6x += f0_; a6y += f1_; ++c6; break;                       \
            default: a7x += f0_; a7y += f1_; ++c7; break;                      \
        }                                                                      \
    }

        for (int j = 0; j < dd; j += 4) {
            int p0 = __shfl(pk, j);
            int p1 = __shfl(pk, min(j + 1, dd - 1));
            int p2 = __shfl(pk, min(j + 2, dd - 1));
            int p3 = __shfl(pk, min(j + 3, dd - 1));
            unsigned u0 = *(const unsigned*)(hbf + (size_t)(p0 & SRCMASK) * HH + lane * 2);
            unsigned u1 = *(const unsigned*)(hbf + (size_t)(p1 & SRCMASK) * HH + lane * 2);
            unsigned u2 = *(const unsigned*)(hbf + (size_t)(p2 & SRCMASK) * HH + lane * 2);
            unsigned u3 = *(const unsigned*)(hbf + (size_t)(p3 & SRCMASK) * HH + lane * 2);
            ACCE(p0, u0);
            if (j + 1 < dd) ACCE(p1, u1);
            if (j + 2 < dd) ACCE(p2, u2);
            if (j + 3 < dd) ACCE(p3, u3);
        }
#undef ACCE

        // write per-relation means to AT[1..8], row dl (zeros for empty relations)
        unsigned short* atp = AT + 32 * LDA + dl * LDA + lane * 2;
#define WR(R, AX, AY, CN)                                                       \
    {                                                                           \
        float inv_ = 1.0f / fmaxf(1.0f, (float)(CN));                           \
        unsigned v_ = (unsigned)f2bf((AX) * inv_) | ((unsigned)f2bf((AY) * inv_) << 16); \
        *(unsigned*)(atp + (R) * 32 * LDA) = v_;                                \
    }
        WR(0, a0x, a0y, c0); WR(1, a1x, a1y, c1); WR(2, a2x, a2y, c2); WR(3, a3x, a3y, c3);
        WR(4, a4x, a4y, c4); WR(5, a5x, a5y, c5); WR(6, a6x, a6y, c6); WR(7, a7x, a7y, c7);
#undef WR
    }
    __syncthreads();

    // ---- 9 accumulating GEMM passes: C[32 x (wave's 32 cols)] += AT[c] @ Bt[c] ----
    const int n0 = wv * 32;
    floatx4 acc[2][2];
#pragma unroll
    for (int a = 0; a < 2; ++a)
#pragma unroll
        for (int b = 0; b < 2; ++b) acc[a][b] = (floatx4){0.f, 0.f, 0.f, 0.f};

    for (int c = 0; c < 9; ++c) {
        const unsigned short* Ap = AT + c * 32 * LDA;
        const unsigned short* Bp = Bt + (size_t)c * HH * HH;
#pragma unroll
        for (int ks = 0; ks < 4; ++ks) {
            short8 a0 = *(const short8*)(Ap + l16 * LDA + ks * 32 + quad * 8);
            short8 a1 = *(const short8*)(Ap + (16 + l16) * LDA + ks * 32 + quad * 8);
#pragma unroll
            for (int nf = 0; nf < 2; ++nf) {
                short8 b = *(const short8*)(Bp + (size_t)(n0 + nf * 16 + l16) * HH + ks * 32 + quad * 8);
                acc[0][nf] = __builtin_amdgcn_mfma_f32_16x16x32_bf16(a0, b, acc[0][nf], 0, 0, 0);
                acc[1][nf] = __builtin_amdgcn_mfma_f32_16x16x32_bf16(a1, b, acc[1][nf], 0, 0, 0);
            }
        }
    }
    __syncthreads();

    // ---- epilogue 1: h2 = relu(C + b2) -> AT[0]; stage lin_w^T bf16 -> AT tile-1 region ----
#pragma unroll
    for (int mf = 0; mf < 2; ++mf)
#pragma unroll
        for (int nf = 0; nf < 2; ++nf) {
            int gcol = n0 + nf * 16 + l16;
            float bb = b2[gcol];
#pragma unroll
            for (int rg = 0; rg < 4; ++rg) {
                int row = mf * 16 + quad * 4 + rg;
                AT[row * LDA + gcol] = f2bf(fmaxf(acc[mf][nf][rg] + bb, 0.f));
            }
        }
    unsigned short* LW = AT + 32 * LDA;   // rows 0..47 x 136 (within tiles 1-2, now free)
#pragma unroll
    for (int it = 0; it < 24; ++it) {
        int id = tid + it * 256;
        int n = id >> 7, k = id & 127;
        LW[n * LDA + k] = (n < CC) ? f2bf(lin_w[(size_t)k * CC + n]) : (unsigned short)0;
    }
    __syncthreads();

    // ---- final linear: waves 0-1, 16 rows each ----
    if (wv < 2) {
        floatx4 a2[3];
#pragma unroll
        for (int nf = 0; nf < 3; ++nf) a2[nf] = (floatx4){0.f, 0.f, 0.f, 0.f};
#pragma unroll
        for (int ks = 0; ks < 4; ++ks) {
            short8 a = *(const short8*)(AT + (wv * 16 + l16) * LDA + ks * 32 + quad * 8);
#pragma unroll
            for (int nf = 0; nf < 3; ++nf) {
                short8 b = *(const short8*)(LW + (nf * 16 + l16) * LDA + ks * 32 + quad * 8);
                a2[nf] = __builtin_amdgcn_mfma_f32_16x16x32_bf16(a, b, a2[nf], 0, 0, 0);
            }
        }
#pragma unroll
        for (int nf = 0; nf < 3; ++nf) {
            int col = nf * 16 + l16;
            if (col < CC) {
                float lb = lin_b[col];
#pragma unroll
                for (int rg = 0; rg < 4; ++rg) {
                    int grow = m0 + wv * 16 + quad * 4 + rg;
                    if (grow < Nn) out[(size_t)grow * CC + col] = a2[nf][rg] + lb;
                }
            }
        }
    }
}

// ---------------- launcher ----------------

extern "C" void kernel_launch(void* const* d_in, const int* in_sizes, int n_in,
                              void* d_out, int out_size, void* d_ws, size_t ws_size,
                              hipStream_t stream) {
    const int* ei      = (const int*)d_in[0];
    const int* et      = (const int*)d_in[1];
    const float* W1    = (const float*)d_in[2];
    const float* root1 = (const float*)d_in[3];
    const float* b1    = (const float*)d_in[4];
    const float* W2    = (const float*)d_in[5];
    const float* root2 = (const float*)d_in[6];
    const float* b2    = (const float*)d_in[7];
    const float* lw    = (const float*)d_in[8];
    const float* lb    = (const float*)d_in[9];
    float* out = (float*)d_out;

    const int E = in_sizes[1];
    const int N = in_sizes[3] / HH;

    // ws: deg[N*16] | elist[N*CAP] ints; then hbf | Bt (bf16)
    int* deg   = (int*)d_ws;
    int* elist = deg + (size_t)N * DEGSTR;
    size_t iofs = (size_t)N * DEGSTR + (size_t)N * CAP;
    iofs = (iofs + 3) & ~(size_t)3;                     // 16B align
    unsigned short* hbf = (unsigned short*)((int*)d_ws + iofs);
    unsigned short* Bt  = hbf + (size_t)N * HH;

    const int* src = ei;
    const int* dst = ei + E;

    hipMemsetAsync(deg, 0, (size_t)N * DEGSTR * sizeof(int), stream);
    fill_kernel<<<(E + 255) / 256, 256, 0, stream>>>(src, dst, et, deg, elist, E);
    tcast_kernel<<<9 * 32, 256, 0, stream>>>(root2, W2, Bt);
    gather1_kernel<<<(N * 64 + 255) / 256, 256, 0, stream>>>(deg, elist, W1, root1, b1, hbf, N);
    layer2_kernel<<<(N + 31) / 32, 256, 0, stream>>>(deg, elist, hbf, Bt, b2, lw, lb, out, N);
}

// Round 7
// 511.597 us; speedup vs baseline: 1.1336x; 1.1336x over previous
//
#include <hip/hip_runtime.h>

#define HH 128
#define RNUM 8
#define CC 40
#define CAP 64                // padded edge slots per dst (P(deg>64) ~ 1e-19)
#define LDA 136               // LDS row stride (bf16): 128 + 8 pad
#define SRCMASK 0x7FFFFFF
#define DEGSTR 16             // deg counter stride in ints: 1 counter per 64-B line

typedef __attribute__((ext_vector_type(8))) short short8;
typedef __attribute__((ext_vector_type(4))) float floatx4;

__device__ __forceinline__ float u2f(unsigned u) {
    union { unsigned u; float f; } c;
    c.u = u;
    return c.f;
}
__device__ __forceinline__ unsigned short f2bf(float f) {
    union { float f; unsigned u; } c;
    c.f = f;
    return (unsigned short)((c.u + 0x7FFFu + ((c.u >> 16) & 1u)) >> 16);
}

// ---------------- edge bucketing: elist[d*64+p] = (rel<<27)|src ----------------
__global__ void fill_kernel(const int* __restrict__ src, const int* __restrict__ dst,
                            const int* __restrict__ et, int* __restrict__ deg,
                            int* __restrict__ elist, int E) {
    int e = blockIdx.x * blockDim.x + threadIdx.x;
    if (e < E) {
        int d = dst[e];
        int p = atomicAdd(&deg[(size_t)d * DEGSTR], 1);
        if (p < CAP) elist[(size_t)d * CAP + p] = (int)(((unsigned)et[e] << 27) | (unsigned)src[e]);
    }
}

// ---------------- fused streaming casts (no atomics in this dispatch) ----------------
// blocks [0, castB): W1 fp32 -> W1b bf16, 8 elems/thread
// blocks [castB, castB+288): Bt[c][n][k] = bf16(Bc[k][n]), c0=root2, c1..8=W2[r]
__global__ void wcast_kernel(const float* __restrict__ W1, unsigned short* __restrict__ W1b,
                             size_t castElems, const float* __restrict__ root2,
                             const float* __restrict__ W2, unsigned short* __restrict__ Bt,
                             int castB) {
    int b = blockIdx.x;
    if (b < castB) {
        size_t i8 = ((size_t)b * 256 + threadIdx.x) * 8;
        if (i8 < castElems) {
            float4 f0 = *(const float4*)(W1 + i8);
            float4 f1 = *(const float4*)(W1 + i8 + 4);
            uint4 o;
            o.x = (unsigned)f2bf(f0.x) | ((unsigned)f2bf(f0.y) << 16);
            o.y = (unsigned)f2bf(f0.z) | ((unsigned)f2bf(f0.w) << 16);
            o.z = (unsigned)f2bf(f1.x) | ((unsigned)f2bf(f1.y) << 16);
            o.w = (unsigned)f2bf(f1.z) | ((unsigned)f2bf(f1.w) << 16);
            *(uint4*)(W1b + i8) = o;
        }
    } else {
        int bid = b - castB;
        int c = bid >> 5;
        int id = (bid & 31) * 256 + threadIdx.x;
        int n = id >> 6, kp = id & 63;
        const float* B = (c == 0) ? root2 : W2 + (size_t)(c - 1) * HH * HH;
        float g0 = B[(2 * kp) * HH + n];
        float g1 = B[(2 * kp + 1) * HH + n];
        unsigned v = (unsigned)f2bf(g0) | ((unsigned)f2bf(g1) << 16);
        *(unsigned*)(Bt + (size_t)c * HH * HH + n * HH + 2 * kp) = v;
    }
}

// ---------------- layer 1: wave per dst; bf16 W1 gather (256 B/edge, L3-resident table) ----
// h[d] = relu( sum_r (1/c_r) * sum_{e in (d,r)} W1b[r, src_e] + root1[d] + b1 )
__global__ void gather1_kernel(const int* __restrict__ deg, const int* __restrict__ elist,
                               const unsigned short* __restrict__ W1b, const float* __restrict__ root1,
                               const float* __restrict__ b1, unsigned short* __restrict__ hbf,
                               int Nn) {
    int w = (blockIdx.x * blockDim.x + threadIdx.x) >> 6;
    if (w >= Nn) return;
    int lane = threadIdx.x & 63;
    int qid = lane >> 4, cl = lane & 15;      // quad gathers one 256 B bf16 row
    int dd = min(deg[(size_t)w * DEGSTR], CAP);
    int pk = elist[(size_t)w * CAP + lane];   // one coalesced 256 B load: slot per lane
    int myrel = (lane < dd) ? (int)((unsigned)pk >> 27) : 8;

    float myinv = 1.0f;
#pragma unroll
    for (int r = 0; r < 8; ++r) {
        unsigned long long m = __ballot(myrel == r);
        int c = __popcll(m);
        if (lane == r) myinv = 1.0f / fmaxf(1.0f, (float)c);
    }

    float s0[8] = {0.f, 0.f, 0.f, 0.f, 0.f, 0.f, 0.f, 0.f};
    float s1[8] = {0.f, 0.f, 0.f, 0.f, 0.f, 0.f, 0.f, 0.f};
    float s2[8] = {0.f, 0.f, 0.f, 0.f, 0.f, 0.f, 0.f, 0.f};
    float s3[8] = {0.f, 0.f, 0.f, 0.f, 0.f, 0.f, 0.f, 0.f};

#define GRP(G, S)                                                                 \
    {                                                                             \
        int j = ((G) << 2) + qid;                                                 \
        int jj = min(j, dd - 1);                                                  \
        int pkj = __shfl(pk, jj);                                                 \
        int rr = (int)((unsigned)pkj >> 27);                                      \
        float wt = __shfl(myinv, rr);                                             \
        int ss = pkj & SRCMASK;                                                   \
        const unsigned short* p = W1b + ((size_t)rr * Nn + ss) * HH + cl * 8;     \
        if (j < dd) {                                                             \
            uint4 v = *(const uint4*)p;                                           \
            S[0] += u2f(v.x << 16) * wt; S[1] += u2f(v.x & 0xFFFF0000u) * wt;     \
            S[2] += u2f(v.y << 16) * wt; S[3] += u2f(v.y & 0xFFFF0000u) * wt;     \
            S[4] += u2f(v.z << 16) * wt; S[5] += u2f(v.z & 0xFFFF0000u) * wt;     \
            S[6] += u2f(v.w << 16) * wt; S[7] += u2f(v.w & 0xFFFF0000u) * wt;     \
        }                                                                         \
    }

    int ng = (dd + 3) >> 2;
    int g = 0;
    for (; g + 3 < ng; g += 4) {
        GRP(g, s0);
        GRP(g + 1, s1);
        GRP(g + 2, s2);
        GRP(g + 3, s3);
    }
    for (; g < ng; ++g) GRP(g, s0);
#undef GRP

#pragma unroll
    for (int k = 0; k < 8; ++k) {
        s0[k] += s1[k] + s2[k] + s3[k];
        s0[k] += __shfl_xor(s0[k], 16);
        s0[k] += __shfl_xor(s0[k], 32);
    }

    if (qid == 0) {
        const float* rp = root1 + (size_t)w * HH + cl * 8;
        float4 r0 = *(const float4*)rp;
        float4 r1 = *(const float4*)(rp + 4);
        float4 c0 = *(const float4*)(b1 + cl * 8);
        float4 c1 = *(const float4*)(b1 + cl * 8 + 4);
        float o[8];
        o[0] = fmaxf(s0[0] + r0.x + c0.x, 0.f); o[1] = fmaxf(s0[1] + r0.y + c0.y, 0.f);
        o[2] = fmaxf(s0[2] + r0.z + c0.z, 0.f); o[3] = fmaxf(s0[3] + r0.w + c0.w, 0.f);
        o[4] = fmaxf(s0[4] + r1.x + c1.x, 0.f); o[5] = fmaxf(s0[5] + r1.y + c1.y, 0.f);
        o[6] = fmaxf(s0[6] + r1.z + c1.z, 0.f); o[7] = fmaxf(s0[7] + r1.w + c1.w, 0.f);
        ushort4 pk0, pk1;
        pk0.x = f2bf(o[0]); pk0.y = f2bf(o[1]); pk0.z = f2bf(o[2]); pk0.w = f2bf(o[3]);
        pk1.x = f2bf(o[4]); pk1.y = f2bf(o[5]); pk1.z = f2bf(o[6]); pk1.w = f2bf(o[7]);
        unsigned short* hp = hbf + (size_t)w * HH + cl * 8;
        *(ushort4*)hp = pk0;
        *(ushort4*)(hp + 4) = pk1;
    }
}

// ---------------- dense transform: xrb[c][n][:] = bf16( h[n] @ Bc ), c=0..8 ----------------
__global__ __launch_bounds__(256, 3) void gemmxr_kernel(
    const unsigned short* __restrict__ hbf, const unsigned short* __restrict__ Bt,
    unsigned short* __restrict__ xrb, int Nn, int nmb) {
    __shared__ unsigned short As[64 * LDA];
    __shared__ unsigned short Bs[128 * LDA];
    const int tid = threadIdx.x;
    const int lane = tid & 63, wv = tid >> 6;          // 4 waves
    const int quad = lane >> 4, l16 = lane & 15;
    const int mr = wv & 1, nc = wv >> 1;               // 2x2 wave tiling
    const int mb = blockIdx.x % nmb;
    const int c = blockIdx.x / nmb;
    const int m0 = mb * 64;

#pragma unroll
    for (int it = 0; it < 4; ++it) {
        int id = tid + it * 256;
        int rw = id >> 4, c8 = id & 15;
        uint4 v = make_uint4(0, 0, 0, 0);
        if (m0 + rw < Nn) v = *(const uint4*)(hbf + (size_t)(m0 + rw) * HH + c8 * 8);
        *(uint4*)(As + rw * LDA + c8 * 8) = v;
    }
    const unsigned short* Bsrc = Bt + (size_t)c * HH * HH;
#pragma unroll
    for (int it = 0; it < 8; ++it) {
        int id = tid + it * 256;
        int rw = id >> 4, c8 = id & 15;
        *(uint4*)(Bs + rw * LDA + c8 * 8) = *(const uint4*)(Bsrc + rw * HH + c8 * 8);
    }
    __syncthreads();

    floatx4 acc[2][4];
#pragma unroll
    for (int a = 0; a < 2; ++a)
#pragma unroll
        for (int bb = 0; bb < 4; ++bb) acc[a][bb] = (floatx4){0.f, 0.f, 0.f, 0.f};

#pragma unroll
    for (int ks = 0; ks < 4; ++ks) {
        short8 a0 = *(const short8*)(As + (mr * 32 + l16) * LDA + ks * 32 + quad * 8);
        short8 a1 = *(const short8*)(As + (mr * 32 + 16 + l16) * LDA + ks * 32 + quad * 8);
#pragma unroll
        for (int nf = 0; nf < 4; ++nf) {
            short8 b = *(const short8*)(Bs + (nc * 64 + nf * 16 + l16) * LDA + ks * 32 + quad * 8);
            acc[0][nf] = __builtin_amdgcn_mfma_f32_16x16x32_bf16(a0, b, acc[0][nf], 0, 0, 0);
            acc[1][nf] = __builtin_amdgcn_mfma_f32_16x16x32_bf16(a1, b, acc[1][nf], 0, 0, 0);
        }
    }

    __syncthreads();
#pragma unroll
    for (int mf = 0; mf < 2; ++mf)
#pragma unroll
        for (int nf = 0; nf < 4; ++nf) {
            int gcol = nc * 64 + nf * 16 + l16;
#pragma unroll
            for (int rg = 0; rg < 4; ++rg) {
                int row = mr * 32 + mf * 16 + quad * 4 + rg;
                Bs[row * LDA + gcol] = f2bf(acc[mf][nf][rg]);
            }
        }
    __syncthreads();
#pragma unroll
    for (int it = 0; it < 4; ++it) {
        int id = tid + it * 256;
        int rw = id >> 4, c8 = id & 15;
        if (m0 + rw < Nn)
            *(uint4*)(xrb + ((size_t)c * Nn + m0 + rw) * HH + c8 * 8) =
                *(const uint4*)(Bs + rw * LDA + c8 * 8);
    }
}

// ---------------- layer 2: wave per dst; bf16 xr gather + self + b2 + relu ----------------
__global__ void gather2_kernel(const int* __restrict__ deg, const int* __restrict__ elist,
                               const unsigned short* __restrict__ xrb, const float* __restrict__ b2,
                               unsigned short* __restrict__ h2bf, int Nn) {
    int w = (blockIdx.x * blockDim.x + threadIdx.x) >> 6;
    if (w >= Nn) return;
    int lane = threadIdx.x & 63;
    int qid = lane >> 4, cl = lane & 15;      // quad gathers one 256 B bf16 row
    int dd = min(deg[(size_t)w * DEGSTR], CAP);
    int pk = elist[(size_t)w * CAP + lane];
    int myrel = (lane < dd) ? (int)((unsigned)pk >> 27) : 8;

    float myinv = 1.0f;
#pragma unroll
    for (int r = 0; r < 8; ++r) {
        unsigned long long m = __ballot(myrel == r);
        int c = __popcll(m);
        if (lane == r) myinv = 1.0f / fmaxf(1.0f, (float)c);
    }

    float s0[8] = {0.f, 0.f, 0.f, 0.f, 0.f, 0.f, 0.f, 0.f};
    float s1[8] = {0.f, 0.f, 0.f, 0.f, 0.f, 0.f, 0.f, 0.f};
    float s2[8] = {0.f, 0.f, 0.f, 0.f, 0.f, 0.f, 0.f, 0.f};
    float s3[8] = {0.f, 0.f, 0.f, 0.f, 0.f, 0.f, 0.f, 0.f};

#define GRP(G, S)                                                                 \
    {                                                                             \
        int j = ((G) << 2) + qid;                                                 \
        int jj = min(j, dd - 1);                                                  \
        int pkj = __shfl(pk, jj);                                                 \
        int rr = (int)((unsigned)pkj >> 27);                                      \
        float wt = __shfl(myinv, rr);                                             \
        int ss = pkj & SRCMASK;                                                   \
        const unsigned short* p = xrb + ((size_t)(rr + 1) * Nn + ss) * HH + cl * 8; \
        if (j < dd) {                                                             \
            uint4 v = *(const uint4*)p;                                           \
            S[0] += u2f(v.x << 16) * wt; S[1] += u2f(v.x & 0xFFFF0000u) * wt;     \
            S[2] += u2f(v.y << 16) * wt; S[3] += u2f(v.y & 0xFFFF0000u) * wt;     \
            S[4] += u2f(v.z << 16) * wt; S[5] += u2f(v.z & 0xFFFF0000u) * wt;     \
            S[6] += u2f(v.w << 16) * wt; S[7] += u2f(v.w & 0xFFFF0000u) * wt;     \
        }                                                                         \
    }

    int ng = (dd + 3) >> 2;
    int g = 0;
    for (; g + 3 < ng; g += 4) {
        GRP(g, s0);
        GRP(g + 1, s1);
        GRP(g + 2, s2);
        GRP(g + 3, s3);
    }
    for (; g < ng; ++g) GRP(g, s0);
#undef GRP

#pragma unroll
    for (int k = 0; k < 8; ++k) {
        s0[k] += s1[k] + s2[k] + s3[k];
        s0[k] += __shfl_xor(s0[k], 16);
        s0[k] += __shfl_xor(s0[k], 32);
    }

    if (qid == 0) {
        uint4 sv = *(const uint4*)(xrb + (size_t)w * HH + cl * 8);
        float4 c0 = *(const float4*)(b2 + cl * 8);
        float4 c1 = *(const float4*)(b2 + cl * 8 + 4);
        float o[8];
        o[0] = fmaxf(s0[0] + u2f(sv.x << 16) + c0.x, 0.f);
        o[1] = fmaxf(s0[1] + u2f(sv.x & 0xFFFF0000u) + c0.y, 0.f);
        o[2] = fmaxf(s0[2] + u2f(sv.y << 16) + c0.z, 0.f);
        o[3] = fmaxf(s0[3] + u2f(sv.y & 0xFFFF0000u) + c0.w, 0.f);
        o[4] = fmaxf(s0[4] + u2f(sv.z << 16) + c1.x, 0.f);
        o[5] = fmaxf(s0[5] + u2f(sv.z & 0xFFFF0000u) + c1.y, 0.f);
        o[6] = fmaxf(s0[6] + u2f(sv.w << 16) + c1.z, 0.f);
        o[7] = fmaxf(s0[7] + u2f(sv.w & 0xFFFF0000u) + c1.w, 0.f);
        ushort4 p0, p1;
        p0.x = f2bf(o[0]); p0.y = f2bf(o[1]); p0.z = f2bf(o[2]); p0.w = f2bf(o[3]);
        p1.x = f2bf(o[4]); p1.y = f2bf(o[5]); p1.z = f2bf(o[6]); p1.w = f2bf(o[7]);
        unsigned short* hp = h2bf + (size_t)w * HH + cl * 8;
        *(ushort4*)hp = p0;
        *(ushort4*)(hp + 4) = p1;
    }
}

// ---------------- final linear: out = h2 @ lin_w + lin_b ----------------
__global__ __launch_bounds__(256, 4) void linout_kernel(
    const unsigned short* __restrict__ h2, const float* __restrict__ lin_w,
    const float* __restrict__ lin_b, float* __restrict__ out, int Nn) {
    __shared__ unsigned short As[64 * LDA];
    __shared__ unsigned short Bs[48 * LDA];
    const int tid = threadIdx.x;
    const int lane = tid & 63, wv = tid >> 6;
    const int quad = lane >> 4, l16 = lane & 15;
    const int m0 = blockIdx.x * 64;

#pragma unroll
    for (int it = 0; it < 4; ++it) {
        int id = tid + it * 256;
        int rw = id >> 4, c8 = id & 15;
        uint4 v = make_uint4(0, 0, 0, 0);
        if (m0 + rw < Nn) v = *(const uint4*)(h2 + (size_t)(m0 + rw) * HH + c8 * 8);
        *(uint4*)(As + rw * LDA + c8 * 8) = v;
    }
#pragma unroll
    for (int it = 0; it < 24; ++it) {
        int id = tid + it * 256;
        int n = id >> 7, k = id & 127;
        Bs[n * LDA + k] = (n < CC) ? f2bf(lin_w[(size_t)k * CC + n]) : (unsigned short)0;
    }
    __syncthreads();

    floatx4 acc2[3];
#pragma unroll
    for (int nf = 0; nf < 3; ++nf) acc2[nf] = (floatx4){0.f, 0.f, 0.f, 0.f};
#pragma unroll
    for (int ks = 0; ks < 4; ++ks) {
        short8 a = *(const short8*)(As + (wv * 16 + l16) * LDA + ks * 32 + quad * 8);
#pragma unroll
        for (int nf = 0; nf < 3; ++nf) {
            short8 b = *(const short8*)(Bs + (nf * 16 + l16) * LDA + ks * 32 + quad * 8);
            acc2[nf] = __builtin_amdgcn_mfma_f32_16x16x32_bf16(a, b, acc2[nf], 0, 0, 0);
        }
    }
#pragma unroll
    for (int nf = 0; nf < 3; ++nf) {
        int col = nf * 16 + l16;
        if (col < CC) {
            float lb = lin_b[col];
#pragma unroll
            for (int rg = 0; rg < 4; ++rg) {
                int grow = m0 + wv * 16 + quad * 4 + rg;
                if (grow < Nn) out[(size_t)grow * CC + col] = acc2[nf][rg] + lb;
            }
        }
    }
}

// ---------------- launcher ----------------

extern "C" void kernel_launch(void* const* d_in, const int* in_sizes, int n_in,
                              void* d_out, int out_size, void* d_ws, size_t ws_size,
                              hipStream_t stream) {
    const int* ei      = (const int*)d_in[0];
    const int* et      = (const int*)d_in[1];
    const float* W1    = (const float*)d_in[2];
    const float* root1 = (const float*)d_in[3];
    const float* b1    = (const float*)d_in[4];
    const float* W2    = (const float*)d_in[5];
    const float* root2 = (const float*)d_in[6];
    const float* b2    = (const float*)d_in[7];
    const float* lw    = (const float*)d_in[8];
    const float* lb    = (const float*)d_in[9];
    float* out = (float*)d_out;

    const int E = in_sizes[1];
    const int N = in_sizes[3] / HH;

    // ws: deg[N*16] | elist[N*CAP] ints; then hbf | W1b | Bt | xrb[9*N*H] | h2 (bf16)
    int* deg   = (int*)d_ws;
    int* elist = deg + (size_t)N * DEGSTR;
    size_t iofs = (size_t)N * DEGSTR + (size_t)N * CAP;
    iofs = (iofs + 3) & ~(size_t)3;                     // 16B align
    unsigned short* hbf  = (unsigned short*)((int*)d_ws + iofs);
    unsigned short* W1b  = hbf + (size_t)N * HH;
    unsigned short* Bt   = W1b + (size_t)N * RNUM * HH;
    unsigned short* xrb  = Bt + (size_t)9 * HH * HH;
    unsigned short* h2bf = xrb + (size_t)9 * N * HH;

    const int* src = ei;
    const int* dst = ei + E;

    const int nmb = (N + 63) / 64;
    const size_t castElems = (size_t)N * RNUM * HH;
    const int castB = (int)((castElems / 8 + 255) / 256);

    hipMemsetAsync(deg, 0, (size_t)N * DEGSTR * sizeof(int), stream);
    fill_kernel<<<(E + 255) / 256, 256, 0, stream>>>(src, dst, et, deg, elist, E);
    wcast_kernel<<<castB + 9 * 32, 256, 0, stream>>>(W1, W1b, castElems, root2, W2, Bt, castB);
    gather1_kernel<<<(N * 64 + 255) / 256, 256, 0, stream>>>(deg, elist, W1b, root1, b1, hbf, N);
    gemmxr_kernel<<<nmb * 9, 256, 0, stream>>>(hbf, Bt, xrb, N, nmb);
    gather2_kernel<<<(N * 64 + 255) / 256, 256, 0, stream>>>(deg, elist, xrb, b2, h2bf, N);
    linout_kernel<<<nmb, 256, 0, stream>>>(h2bf, lw, lb, out, N);
}